// Round 2
// baseline (1099.923 us; speedup 1.0000x reference)
//
#include <hip/hip_runtime.h>
#include <hip/hip_bf16.h>
#include <cstdio>
#include <cstdint>

#define N_TOK 8192
#define D_DIM 2048
#define H_DIM 2048
#define N_EXP 8
#define TOP_K 2
#define NT_CP (N_TOK * TOP_K)
#define BM 128
#define BN 128
#define BK 64
#define MT_MAX 32  /* CAP/BM */

typedef __attribute__((ext_vector_type(4))) float f32x4;
typedef __attribute__((ext_vector_type(8))) short s16x8;
typedef __attribute__((ext_vector_type(4))) short s16x4;

static constexpr size_t OFF_CNT  = 0;
static constexpr size_t OFF_ROWS = 256;
static constexpr size_t OFF_WTS  = OFF_ROWS + (size_t)(NT_CP + 128) * 4;
static constexpr size_t OFF_XB   = OFF_WTS  + (size_t)(NT_CP + 128) * 4;
static constexpr size_t OFF_ACT  = OFF_XB   + (size_t)N_TOK * D_DIM * 2;
static constexpr size_t OFF_W1T  = OFF_ACT  + (size_t)(NT_CP + 128) * H_DIM * 2;
static constexpr size_t OFF_W3T  = OFF_W1T  + (size_t)N_EXP * (size_t)H_DIM * D_DIM * 2;
static constexpr size_t OFF_W2T  = OFF_W3T  + (size_t)N_EXP * (size_t)H_DIM * D_DIM * 2;
static constexpr size_t WS_NEED  = OFF_W2T  + (size_t)N_EXP * (size_t)H_DIM * D_DIM * 2;

__device__ __forceinline__ short f2bf(float f) {
    uint32_t u = __builtin_bit_cast(uint32_t, f);
    uint32_t r = (u + 0x7FFFu + ((u >> 16) & 1u)) >> 16;
    return (short)r;
}

#define GLOAD_LDS16(g, l)                                                                  \
    __builtin_amdgcn_global_load_lds((const __attribute__((address_space(1))) void*)(g),   \
                                     (__attribute__((address_space(3))) void*)(l), 16, 0, 0)

// ---------------- routing: packed slot assignment per expert ----------------
__global__ void routing_kernel(const int* __restrict__ eidx, const float* __restrict__ ew,
                               const int* __restrict__ bspe, int* __restrict__ cnt,
                               int* __restrict__ rows, float* __restrict__ wts) {
    int i = blockIdx.x * blockDim.x + threadIdx.x;
    if (i >= NT_CP) return;
    int e = eidx[i];
    int off = 0;
#pragma unroll
    for (int j = 0; j < N_EXP; ++j) off += (j < e) ? bspe[j] : 0;
    int slot = atomicAdd(&cnt[e], 1);
    rows[off + slot] = i / TOP_K;
    wts[off + slot]  = ew[i];
}

// ---------------- cast x (fp32 -> bf16), vectorized ----------------
__global__ void cast_x_kernel(const float* __restrict__ x, short* __restrict__ xb) {
    int i = blockIdx.x * blockDim.x + threadIdx.x;
    const int total = N_TOK * D_DIM / 4;
    if (i >= total) return;
    f32x4 v = ((const f32x4*)x)[i];
    s16x4 o;
    o.x = f2bf(v.x); o.y = f2bf(v.y); o.z = f2bf(v.z); o.w = f2bf(v.w);
    ((s16x4*)xb)[i] = o;
}

// ---------------- transpose+cast: (E,R,C) fp32 -> (E,C,R) bf16 ----------------
__global__ void transpose_cast_kernel(const float* __restrict__ in, short* __restrict__ out,
                                      int R, int C) {
    __shared__ float tile[32][33];
    int e = blockIdx.z;
    int c0 = blockIdx.x * 32, r0 = blockIdx.y * 32;
    const float* ine = in + (size_t)e * R * C;
    short* oute = out + (size_t)e * R * C;
    int tx = threadIdx.x, ty = threadIdx.y;  // 32 x 8
#pragma unroll
    for (int j = 0; j < 4; ++j)
        tile[ty + j * 8][tx] = ine[(size_t)(r0 + ty + j * 8) * C + c0 + tx];
    __syncthreads();
#pragma unroll
    for (int j = 0; j < 4; ++j)
        oute[(size_t)(c0 + ty + j * 8) * R + r0 + tx] = f2bf(tile[tx][ty + j * 8]);
}

// ---------------- GEMM1: act = silu(x@w1) * (x@w3), gathered A, dual B ----------------
__launch_bounds__(256, 2)
__global__ void gemm1_kernel(const short* __restrict__ xb, const short* __restrict__ w1t,
                             const short* __restrict__ w3t, const int* __restrict__ rows,
                             const int* __restrict__ bspe, short* __restrict__ act) {
    const int e = blockIdx.z;
    const int cnt_e = bspe[e];
    const int mt = blockIdx.y;
    if (mt * BM >= cnt_e) return;
    int off_e = 0;
#pragma unroll
    for (int j = 0; j < N_EXP; ++j) off_e += (j < e) ? bspe[j] : 0;
    const int p0 = off_e + mt * BM;
    const int bn0 = blockIdx.x * BN;
    int valid_rows = cnt_e - mt * BM;
    if (valid_rows > BM) valid_rows = BM;

    __shared__ short sA[BM * BK];
    __shared__ short sB1[BN * BK];
    __shared__ short sB3[BN * BK];

    const int tid = threadIdx.x;
    const int lane = tid & 63;
    const int wid = tid >> 6;

    // per-thread gathered A source addresses (4 staging issues x 32 rows)
    const short* a_src[4];
#pragma unroll
    for (int i = 0; i < 4; ++i) {
        int r = i * 32 + (tid >> 3);
        int tok = (r < valid_rows) ? rows[p0 + r] : rows[p0];
        a_src[i] = xb + (size_t)tok * D_DIM + (tid & 7) * 8;
    }
    const short* b1_src = w1t + ((size_t)e * H_DIM + bn0 + (tid >> 3)) * D_DIM + (tid & 7) * 8;
    const short* b3_src = w3t + ((size_t)e * H_DIM + bn0 + (tid >> 3)) * D_DIM + (tid & 7) * 8;

    f32x4 acc1[4][4], acc3[4][4];
#pragma unroll
    for (int mi = 0; mi < 4; ++mi)
#pragma unroll
        for (int ni = 0; ni < 4; ++ni) {
            acc1[mi][ni] = (f32x4){0.f, 0.f, 0.f, 0.f};
            acc3[mi][ni] = (f32x4){0.f, 0.f, 0.f, 0.f};
        }

    const int wm = (wid >> 1) * 64;
    const int wn = (wid & 1) * 64;

    for (int k0 = 0; k0 < D_DIM; k0 += BK) {
#pragma unroll
        for (int i = 0; i < 4; ++i)
            GLOAD_LDS16(a_src[i] + k0, &sA[(i * 32 + wid * 8) * BK]);
#pragma unroll
        for (int i = 0; i < 4; ++i)
            GLOAD_LDS16(b1_src + (size_t)i * 32 * D_DIM + k0, &sB1[(i * 32 + wid * 8) * BK]);
#pragma unroll
        for (int i = 0; i < 4; ++i)
            GLOAD_LDS16(b3_src + (size_t)i * 32 * D_DIM + k0, &sB3[(i * 32 + wid * 8) * BK]);
        __syncthreads();
#pragma unroll
        for (int kk = 0; kk < 2; ++kk) {
            s16x8 af[4], b1f[4], b3f[4];
#pragma unroll
            for (int mi = 0; mi < 4; ++mi)
                af[mi] = *(const s16x8*)&sA[(wm + mi * 16 + (lane & 15)) * BK + kk * 32 + (lane >> 4) * 8];
#pragma unroll
            for (int ni = 0; ni < 4; ++ni) {
                b1f[ni] = *(const s16x8*)&sB1[(wn + ni * 16 + (lane & 15)) * BK + kk * 32 + (lane >> 4) * 8];
                b3f[ni] = *(const s16x8*)&sB3[(wn + ni * 16 + (lane & 15)) * BK + kk * 32 + (lane >> 4) * 8];
            }
#pragma unroll
            for (int mi = 0; mi < 4; ++mi)
#pragma unroll
                for (int ni = 0; ni < 4; ++ni) {
                    acc1[mi][ni] = __builtin_amdgcn_mfma_f32_16x16x32_bf16(af[mi], b1f[ni], acc1[mi][ni], 0, 0, 0);
                    acc3[mi][ni] = __builtin_amdgcn_mfma_f32_16x16x32_bf16(af[mi], b3f[ni], acc3[mi][ni], 0, 0, 0);
                }
        }
        __syncthreads();
    }

    // epilogue: silu(g)*u -> bf16 act (C/D layout: col=lane&15, row=(lane>>4)*4+j)
#pragma unroll
    for (int mi = 0; mi < 4; ++mi) {
#pragma unroll
        for (int j = 0; j < 4; ++j) {
            int row = wm + mi * 16 + (lane >> 4) * 4 + j;
            if (row < valid_rows) {
                size_t base = (size_t)(p0 + row) * H_DIM + bn0 + wn;
#pragma unroll
                for (int ni = 0; ni < 4; ++ni) {
                    float g = acc1[mi][ni][j];
                    float u = acc3[mi][ni][j];
                    float s = g / (1.0f + __expf(-g));
                    act[base + ni * 16 + (lane & 15)] = f2bf(s * u);
                }
            }
        }
    }
}

// ---------------- GEMM2: y += w * (act @ w2), fused atomic scatter ----------------
__launch_bounds__(256, 2)
__global__ void gemm2_kernel(const short* __restrict__ act, const short* __restrict__ w2t,
                             const int* __restrict__ rows, const float* __restrict__ wts,
                             const int* __restrict__ bspe, float* __restrict__ y) {
    const int e = blockIdx.z;
    const int cnt_e = bspe[e];
    const int mt = blockIdx.y;
    if (mt * BM >= cnt_e) return;
    int off_e = 0;
#pragma unroll
    for (int j = 0; j < N_EXP; ++j) off_e += (j < e) ? bspe[j] : 0;
    const int p0 = off_e + mt * BM;
    const int bn0 = blockIdx.x * BN;
    int valid_rows = cnt_e - mt * BM;
    if (valid_rows > BM) valid_rows = BM;

    __shared__ short sA[BM * BK];
    __shared__ short sB[BN * BK];

    const int tid = threadIdx.x;
    const int lane = tid & 63;
    const int wid = tid >> 6;

    const short* a_src = act + (size_t)(p0 + (tid >> 3)) * H_DIM + (tid & 7) * 8;
    const short* b_src = w2t + ((size_t)e * D_DIM + bn0 + (tid >> 3)) * H_DIM + (tid & 7) * 8;

    f32x4 acc[4][4];
#pragma unroll
    for (int mi = 0; mi < 4; ++mi)
#pragma unroll
        for (int ni = 0; ni < 4; ++ni) acc[mi][ni] = (f32x4){0.f, 0.f, 0.f, 0.f};

    const int wm = (wid >> 1) * 64;
    const int wn = (wid & 1) * 64;

    for (int k0 = 0; k0 < H_DIM; k0 += BK) {
#pragma unroll
        for (int i = 0; i < 4; ++i)
            GLOAD_LDS16(a_src + (size_t)i * 32 * H_DIM + k0, &sA[(i * 32 + wid * 8) * BK]);
#pragma unroll
        for (int i = 0; i < 4; ++i)
            GLOAD_LDS16(b_src + (size_t)i * 32 * H_DIM + k0, &sB[(i * 32 + wid * 8) * BK]);
        __syncthreads();
#pragma unroll
        for (int kk = 0; kk < 2; ++kk) {
            s16x8 af[4], bf[4];
#pragma unroll
            for (int mi = 0; mi < 4; ++mi)
                af[mi] = *(const s16x8*)&sA[(wm + mi * 16 + (lane & 15)) * BK + kk * 32 + (lane >> 4) * 8];
#pragma unroll
            for (int ni = 0; ni < 4; ++ni)
                bf[ni] = *(const s16x8*)&sB[(wn + ni * 16 + (lane & 15)) * BK + kk * 32 + (lane >> 4) * 8];
#pragma unroll
            for (int mi = 0; mi < 4; ++mi)
#pragma unroll
                for (int ni = 0; ni < 4; ++ni)
                    acc[mi][ni] = __builtin_amdgcn_mfma_f32_16x16x32_bf16(af[mi], bf[ni], acc[mi][ni], 0, 0, 0);
        }
        __syncthreads();
    }

#pragma unroll
    for (int mi = 0; mi < 4; ++mi) {
#pragma unroll
        for (int j = 0; j < 4; ++j) {
            int row = wm + mi * 16 + (lane >> 4) * 4 + j;
            if (row < valid_rows) {
                int p = p0 + row;
                int tok = rows[p];
                float w = wts[p];
                float* ybase = y + (size_t)tok * D_DIM + bn0 + wn + (lane & 15);
#pragma unroll
                for (int ni = 0; ni < 4; ++ni)
                    atomicAdd(ybase + ni * 16, acc[mi][ni][j] * w);
            }
        }
    }
}

extern "C" void kernel_launch(void* const* d_in, const int* in_sizes, int n_in,
                              void* d_out, int out_size, void* d_ws, size_t ws_size,
                              hipStream_t stream) {
    const float* x    = (const float*)d_in[0];
    const float* ew   = (const float*)d_in[1];
    const float* w1   = (const float*)d_in[2];
    const float* w2   = (const float*)d_in[3];
    const float* w3   = (const float*)d_in[4];
    const int* eidx   = (const int*)d_in[5];
    const int* bspe   = (const int*)d_in[6];
    float* y          = (float*)d_out;
    char* ws          = (char*)d_ws;

    if (ws_size < WS_NEED) {
        fprintf(stderr, "[kernel] ws too small: have %zu need %zu\n", ws_size, WS_NEED);
        return;
    }

    int*   cnt  = (int*)(ws + OFF_CNT);
    int*   rows = (int*)(ws + OFF_ROWS);
    float* wts  = (float*)(ws + OFF_WTS);
    short* xb   = (short*)(ws + OFF_XB);
    short* act  = (short*)(ws + OFF_ACT);
    short* w1t  = (short*)(ws + OFF_W1T);
    short* w3t  = (short*)(ws + OFF_W3T);
    short* w2t  = (short*)(ws + OFF_W2T);

    hipMemsetAsync(cnt, 0, 256, stream);
    hipMemsetAsync(y, 0, (size_t)N_TOK * D_DIM * 4, stream);

    routing_kernel<<<NT_CP / 256, 256, 0, stream>>>(eidx, ew, bspe, cnt, rows, wts);
    cast_x_kernel<<<(N_TOK * D_DIM / 4) / 256, 256, 0, stream>>>(x, xb);

    dim3 tgrid(H_DIM / 32, D_DIM / 32, N_EXP);
    transpose_cast_kernel<<<tgrid, dim3(32, 8), 0, stream>>>(w1, w1t, D_DIM, H_DIM);
    transpose_cast_kernel<<<tgrid, dim3(32, 8), 0, stream>>>(w3, w3t, D_DIM, H_DIM);
    transpose_cast_kernel<<<dim3(D_DIM / 32, H_DIM / 32, N_EXP), dim3(32, 8), 0, stream>>>(w2, w2t, H_DIM, D_DIM);

    gemm1_kernel<<<dim3(H_DIM / BN, MT_MAX, N_EXP), 256, 0, stream>>>(xb, w1t, w3t, rows, bspe, act);
    gemm2_kernel<<<dim3(D_DIM / BN, MT_MAX, N_EXP), 256, 0, stream>>>(act, w2t, rows, wts, bspe, y);
}

// Round 5
// 1071.684 us; speedup vs baseline: 1.0263x; 1.0263x over previous
//
#include <hip/hip_runtime.h>
#include <hip/hip_bf16.h>
#include <cstdio>
#include <cstdint>

#define N_TOK 8192
#define D_DIM 2048
#define H_DIM 2048
#define N_EXP 8
#define TOP_K 2
#define NT_CP (N_TOK * TOP_K)
#define BM 128
#define BN 128
#define BK 64
#define MT_MAX 32  /* CAP/BM */

typedef __attribute__((ext_vector_type(4))) float f32x4;
typedef __attribute__((ext_vector_type(8))) short s16x8;
typedef __attribute__((ext_vector_type(4))) short s16x4;

static constexpr size_t OFF_CNT  = 0;
static constexpr size_t OFF_ROWS = 256;
static constexpr size_t OFF_WTS  = OFF_ROWS + (size_t)(NT_CP + 128) * 4;
static constexpr size_t OFF_XB   = OFF_WTS  + (size_t)(NT_CP + 128) * 4;
static constexpr size_t OFF_ACT  = OFF_XB   + (size_t)N_TOK * D_DIM * 2;
static constexpr size_t OFF_W13T = OFF_ACT  + (size_t)(NT_CP + 128) * H_DIM * 2;
static constexpr size_t OFF_W2T  = OFF_W13T + (size_t)N_EXP * 4096 * (size_t)D_DIM * 2;
static constexpr size_t WS_NEED  = OFF_W2T  + (size_t)N_EXP * (size_t)H_DIM * D_DIM * 2;

__device__ __forceinline__ short f2bf(float f) {
    uint32_t u = __builtin_bit_cast(uint32_t, f);
    uint32_t r = (u + 0x7FFFu + ((u >> 16) & 1u)) >> 16;
    return (short)r;
}

#define GLOAD_LDS16(g, l)                                                                  \
    __builtin_amdgcn_global_load_lds((const __attribute__((address_space(1))) void*)(g),   \
                                     (__attribute__((address_space(3))) void*)(l), 16, 0, 0)

// ---------------- routing: packed slot assignment per expert ----------------
__global__ void routing_kernel(const int* __restrict__ eidx, const float* __restrict__ ew,
                               const int* __restrict__ bspe, int* __restrict__ cnt,
                               int* __restrict__ rows, float* __restrict__ wts) {
    int i = blockIdx.x * blockDim.x + threadIdx.x;
    if (i >= NT_CP) return;
    int e = eidx[i];
    int off = 0;
#pragma unroll
    for (int j = 0; j < N_EXP; ++j) off += (j < e) ? bspe[j] : 0;
    int slot = atomicAdd(&cnt[e], 1);
    rows[off + slot] = i / TOP_K;
    wts[off + slot]  = ew[i];
}

// ---------------- cast x (fp32 -> bf16), vectorized ----------------
__global__ void cast_x_kernel(const float* __restrict__ x, short* __restrict__ xb) {
    int i = blockIdx.x * blockDim.x + threadIdx.x;
    const int total = N_TOK * D_DIM / 4;
    if (i >= total) return;
    f32x4 v = ((const f32x4*)x)[i];
    s16x4 o;
    o.x = f2bf(v.x); o.y = f2bf(v.y); o.z = f2bf(v.z); o.w = f2bf(v.w);
    ((s16x4*)xb)[i] = o;
}

// ---------------- fused transpose+cast ----------------
// mats 0/1 (w1/w3) -> interleaved w13t[e]: row = (h/16)*32 + sel*16 + (h%16), col = d.
// mat 2 (w2) -> w2t[e]: row = d-col of w2, col = h. 64x64 tile, 256 threads.
// Loads float4 (256B/16-lane group); stores s16x8 (128B/8-lane group); LDS [64][65] = 2-way only.
__global__ void transpose_cast_fused(const float* __restrict__ w1, const float* __restrict__ w3,
                                     const float* __restrict__ w2, short* __restrict__ w13t,
                                     short* __restrict__ w2t) {
    __shared__ float t[64][65];
    const int slab = blockIdx.z;           // 0..23
    const int mat = slab >> 3, e = slab & 7;
    const float* in = (mat == 0 ? w1 : (mat == 1 ? w3 : w2)) + (size_t)e * D_DIM * H_DIM;
    short* out = (mat == 2) ? (w2t + (size_t)e * D_DIM * H_DIM)
                            : (w13t + (size_t)e * 4096 * D_DIM);
    const int r0 = blockIdx.y * 64, c0 = blockIdx.x * 64;
    const int tid = threadIdx.x;

#pragma unroll
    for (int p = 0; p < 4; ++p) {
        int r = p * 16 + (tid >> 4);
        int c4 = (tid & 15) * 4;
        f32x4 v = *(const f32x4*)&in[(size_t)(r0 + r) * 2048 + c0 + c4];
        t[r][c4 + 0] = v.x; t[r][c4 + 1] = v.y; t[r][c4 + 2] = v.z; t[r][c4 + 3] = v.w;
    }
    __syncthreads();
#pragma unroll
    for (int p = 0; p < 2; ++p) {
        int c = c0 + p * 32 + (tid >> 3);           // source column (h for w1/w3, d for w2)
        int r8 = (tid & 7) * 8;
        s16x8 o;
#pragma unroll
        for (int j = 0; j < 8; ++j) o[j] = f2bf(t[r8 + j][c - c0]);
        int row2 = (mat == 2) ? c : (((c >> 4) << 5) + ((mat == 1) ? 16 : 0) + (c & 15));
        *(s16x8*)&out[(size_t)row2 * 2048 + r0 + r8] = o;
    }
}

// ---------------- GEMM1: act = silu(x@w1) * (x@w3) via interleaved B, gathered A ----------------
// B = w13t (4096 x 2048 per expert). Fragment ni pairs: (2p, 2p+1) = (g, u) same lane/h.
__launch_bounds__(256, 2)
__global__ void gemm1_kernel(const short* __restrict__ xb, const short* __restrict__ w13t,
                             const int* __restrict__ rows, const int* __restrict__ bspe,
                             short* __restrict__ act) {
    const int e = blockIdx.z;
    const int cnt_e = bspe[e];
    const int mt = blockIdx.y;
    if (mt * BM >= cnt_e) return;
    int off_e = 0;
#pragma unroll
    for (int j = 0; j < N_EXP; ++j) off_e += (j < e) ? bspe[j] : 0;
    const int p0 = off_e + mt * BM;
    const int bn0 = blockIdx.x * BN;   // row offset in interleaved B (0..4095)
    int valid_rows = cnt_e - mt * BM;
    if (valid_rows > BM) valid_rows = BM;

    __shared__ short sA[BM * BK];
    __shared__ short sB[BN * BK];

    const int tid = threadIdx.x;
    const int lane = tid & 63;
    const int wid = tid >> 6;

    const short* a_src[4];
#pragma unroll
    for (int i = 0; i < 4; ++i) {
        int r = i * 32 + (tid >> 3);
        int tok = (r < valid_rows) ? rows[p0 + r] : rows[p0];
        a_src[i] = xb + (size_t)tok * D_DIM + (tid & 7) * 8;
    }
    const short* b_src = w13t + ((size_t)e * 4096 + bn0 + (tid >> 3)) * D_DIM + (tid & 7) * 8;

    f32x4 acc[4][4];
#pragma unroll
    for (int mi = 0; mi < 4; ++mi)
#pragma unroll
        for (int ni = 0; ni < 4; ++ni) acc[mi][ni] = (f32x4){0.f, 0.f, 0.f, 0.f};

    const int wm = (wid >> 1) * 64;
    const int wn = (wid & 1) * 64;

    for (int k0 = 0; k0 < D_DIM; k0 += BK) {
#pragma unroll
        for (int i = 0; i < 4; ++i)
            GLOAD_LDS16(a_src[i] + k0, &sA[(i * 32 + wid * 8) * BK]);
#pragma unroll
        for (int i = 0; i < 4; ++i)
            GLOAD_LDS16(b_src + (size_t)i * 32 * D_DIM + k0, &sB[(i * 32 + wid * 8) * BK]);
        __syncthreads();
#pragma unroll
        for (int kk = 0; kk < 2; ++kk) {
            s16x8 af[4], bf[4];
#pragma unroll
            for (int mi = 0; mi < 4; ++mi)
                af[mi] = *(const s16x8*)&sA[(wm + mi * 16 + (lane & 15)) * BK + kk * 32 + (lane >> 4) * 8];
#pragma unroll
            for (int ni = 0; ni < 4; ++ni)
                bf[ni] = *(const s16x8*)&sB[(wn + ni * 16 + (lane & 15)) * BK + kk * 32 + (lane >> 4) * 8];
#pragma unroll
            for (int mi = 0; mi < 4; ++mi)
#pragma unroll
                for (int ni = 0; ni < 4; ++ni)
                    acc[mi][ni] = __builtin_amdgcn_mfma_f32_16x16x32_bf16(af[mi], bf[ni], acc[mi][ni], 0, 0, 0);
        }
        __syncthreads();
    }

    // epilogue: pair (2p, 2p+1) = (g, u); h = (bn0+wn)/2 + p*16 + (lane&15)
    const int hbase = (bn0 + wn) >> 1;
#pragma unroll
    for (int mi = 0; mi < 4; ++mi) {
#pragma unroll
        for (int j = 0; j < 4; ++j) {
            int row = wm + mi * 16 + (lane >> 4) * 4 + j;
            if (row < valid_rows) {
                size_t base = (size_t)(p0 + row) * H_DIM + hbase + (lane & 15);
#pragma unroll
                for (int p = 0; p < 2; ++p) {
                    float g = acc[mi][2 * p][j];
                    float u = acc[mi][2 * p + 1][j];
                    float s = g / (1.0f + __expf(-g));
                    act[base + p * 16] = f2bf(s * u);
                }
            }
        }
    }
}

// ---------------- GEMM2: y += w * (act @ w2), fused atomic scatter ----------------
__launch_bounds__(256, 2)
__global__ void gemm2_kernel(const short* __restrict__ act, const short* __restrict__ w2t,
                             const int* __restrict__ rows, const float* __restrict__ wts,
                             const int* __restrict__ bspe, float* __restrict__ y) {
    const int e = blockIdx.z;
    const int cnt_e = bspe[e];
    const int mt = blockIdx.y;
    if (mt * BM >= cnt_e) return;
    int off_e = 0;
#pragma unroll
    for (int j = 0; j < N_EXP; ++j) off_e += (j < e) ? bspe[j] : 0;
    const int p0 = off_e + mt * BM;
    const int bn0 = blockIdx.x * BN;
    int valid_rows = cnt_e - mt * BM;
    if (valid_rows > BM) valid_rows = BM;

    __shared__ short sA[BM * BK];
    __shared__ short sB[BN * BK];

    const int tid = threadIdx.x;
    const int lane = tid & 63;
    const int wid = tid >> 6;

    const short* a_src = act + (size_t)(p0 + (tid >> 3)) * H_DIM + (tid & 7) * 8;
    const short* b_src = w2t + ((size_t)e * D_DIM + bn0 + (tid >> 3)) * H_DIM + (tid & 7) * 8;

    f32x4 acc[4][4];
#pragma unroll
    for (int mi = 0; mi < 4; ++mi)
#pragma unroll
        for (int ni = 0; ni < 4; ++ni) acc[mi][ni] = (f32x4){0.f, 0.f, 0.f, 0.f};

    const int wm = (wid >> 1) * 64;
    const int wn = (wid & 1) * 64;

    for (int k0 = 0; k0 < H_DIM; k0 += BK) {
#pragma unroll
        for (int i = 0; i < 4; ++i)
            GLOAD_LDS16(a_src + (size_t)i * 32 * H_DIM + k0, &sA[(i * 32 + wid * 8) * BK]);
#pragma unroll
        for (int i = 0; i < 4; ++i)
            GLOAD_LDS16(b_src + (size_t)i * 32 * H_DIM + k0, &sB[(i * 32 + wid * 8) * BK]);
        __syncthreads();
#pragma unroll
        for (int kk = 0; kk < 2; ++kk) {
            s16x8 af[4], bf[4];
#pragma unroll
            for (int mi = 0; mi < 4; ++mi)
                af[mi] = *(const s16x8*)&sA[(wm + mi * 16 + (lane & 15)) * BK + kk * 32 + (lane >> 4) * 8];
#pragma unroll
            for (int ni = 0; ni < 4; ++ni)
                bf[ni] = *(const s16x8*)&sB[(wn + ni * 16 + (lane & 15)) * BK + kk * 32 + (lane >> 4) * 8];
#pragma unroll
            for (int mi = 0; mi < 4; ++mi)
#pragma unroll
                for (int ni = 0; ni < 4; ++ni)
                    acc[mi][ni] = __builtin_amdgcn_mfma_f32_16x16x32_bf16(af[mi], bf[ni], acc[mi][ni], 0, 0, 0);
        }
        __syncthreads();
    }

#pragma unroll
    for (int mi = 0; mi < 4; ++mi) {
#pragma unroll
        for (int j = 0; j < 4; ++j) {
            int row = wm + mi * 16 + (lane >> 4) * 4 + j;
            if (row < valid_rows) {
                int p = p0 + row;
                int tok = rows[p];
                float w = wts[p];
                float* ybase = y + (size_t)tok * D_DIM + bn0 + wn + (lane & 15);
#pragma unroll
                for (int ni = 0; ni < 4; ++ni)
                    atomicAdd(ybase + ni * 16, acc[mi][ni][j] * w);
            }
        }
    }
}

extern "C" void kernel_launch(void* const* d_in, const int* in_sizes, int n_in,
                              void* d_out, int out_size, void* d_ws, size_t ws_size,
                              hipStream_t stream) {
    const float* x    = (const float*)d_in[0];
    const float* ew   = (const float*)d_in[1];
    const float* w1   = (const float*)d_in[2];
    const float* w2   = (const float*)d_in[3];
    const float* w3   = (const float*)d_in[4];
    const int* eidx   = (const int*)d_in[5];
    const int* bspe   = (const int*)d_in[6];
    float* y          = (float*)d_out;
    char* ws          = (char*)d_ws;

    if (ws_size < WS_NEED) {
        fprintf(stderr, "[kernel] ws too small: have %zu need %zu\n", ws_size, WS_NEED);
        return;
    }

    int*   cnt  = (int*)(ws + OFF_CNT);
    int*   rows = (int*)(ws + OFF_ROWS);
    float* wts  = (float*)(ws + OFF_WTS);
    short* xb   = (short*)(ws + OFF_XB);
    short* act  = (short*)(ws + OFF_ACT);
    short* w13t = (short*)(ws + OFF_W13T);
    short* w2t  = (short*)(ws + OFF_W2T);

    hipMemsetAsync(cnt, 0, 256, stream);
    hipMemsetAsync(y, 0, (size_t)N_TOK * D_DIM * 4, stream);

    routing_kernel<<<NT_CP / 256, 256, 0, stream>>>(eidx, ew, bspe, cnt, rows, wts);
    cast_x_kernel<<<(N_TOK * D_DIM / 4) / 256, 256, 0, stream>>>(x, xb);

    transpose_cast_fused<<<dim3(2048 / 64, 2048 / 64, 24), 256, 0, stream>>>(w1, w3, w2, w13t, w2t);

    gemm1_kernel<<<dim3(4096 / BN, MT_MAX, N_EXP), 256, 0, stream>>>(xb, w13t, rows, bspe, act);
    gemm2_kernel<<<dim3(D_DIM / BN, MT_MAX, N_EXP), 256, 0, stream>>>(act, w2t, rows, wts, bspe, y);
}